// Round 1
// baseline (5537.732 us; speedup 1.0000x reference)
//
#include <hip/hip_runtime.h>
#include <math.h>

namespace {
constexpr int B = 2;
constexpr int N = 2048;
constexpr int DIM = 512;
constexpr int H = 8;
constexpr int DH = 64;
constexpr int MEM = 16;
constexpr int J = MEM + N;       // 2064
constexpr float SCALE = 0.125f;  // 64^-0.5
}

// ---------------- K1: fused QKV projection GEMM ----------------
// grid (4096/64, 512/64, 3), block 256. out = x @ {Wq,Wk,Wv}, scattered into
// q[b,h,n,dh] and k/v[b,h,MEM+n,dh] head-split layouts.
__global__ __launch_bounds__(256)
void qkv_gemm(const float* __restrict__ x, const float* __restrict__ Wq,
              const float* __restrict__ Wk, const float* __restrict__ Wv,
              float* __restrict__ qb, float* __restrict__ kb, float* __restrict__ vb)
{
    const int m0 = blockIdx.x * 64;
    const int c0 = blockIdx.y * 64;
    const int which = blockIdx.z;
    const float* __restrict__ W = (which == 0) ? Wq : (which == 1) ? Wk : Wv;

    __shared__ __align__(16) float As[16][68];  // [k][m], 68 stride: 16B-aligned + 2-way-max banks
    __shared__ __align__(16) float Bs[16][64];  // [k][c]

    const int t = threadIdx.x;
    const int tr = t >> 4, tc = t & 15;
    float acc[4][4];
#pragma unroll
    for (int i = 0; i < 4; ++i)
#pragma unroll
        for (int j2 = 0; j2 < 4; ++j2) acc[i][j2] = 0.f;

    const int ar = t >> 2, ac4 = (t & 3) * 4;   // A: 64 rows x 16 cols
    const int br = t >> 4, bc4 = (t & 15) * 4;  // B: 16 rows x 64 cols

    for (int k0 = 0; k0 < DIM; k0 += 16) {
        const float4 av = *(const float4*)(x + (size_t)(m0 + ar) * DIM + (k0 + ac4));
        const float4 bv = *(const float4*)(W + (size_t)(k0 + br) * DIM + (c0 + bc4));
        __syncthreads();  // previous tile fully consumed
        As[ac4 + 0][ar] = av.x; As[ac4 + 1][ar] = av.y;
        As[ac4 + 2][ar] = av.z; As[ac4 + 3][ar] = av.w;
        *(float4*)(&Bs[br][bc4]) = bv;
        __syncthreads();
#pragma unroll
        for (int kk = 0; kk < 16; ++kk) {
            const float4 a4 = *(const float4*)(&As[kk][tr * 4]);
            const float4 b4 = *(const float4*)(&Bs[kk][tc * 4]);
            const float aarr[4] = {a4.x, a4.y, a4.z, a4.w};
            const float barr[4] = {b4.x, b4.y, b4.z, b4.w};
#pragma unroll
            for (int i = 0; i < 4; ++i)
#pragma unroll
                for (int j2 = 0; j2 < 4; ++j2)
                    acc[i][j2] = fmaf(aarr[i], barr[j2], acc[i][j2]);
        }
    }

    const int h0 = c0 >> 6;        // c0 is a multiple of 64
    const int dbase = tc * 4;      // d within head
#pragma unroll
    for (int i = 0; i < 4; ++i) {
        const int m = m0 + tr * 4 + i;
        const int bidx = m >> 11, ii = m & (N - 1);
        const float4 o = make_float4(acc[i][0], acc[i][1], acc[i][2], acc[i][3]);
        if (which == 0)
            *(float4*)(qb + ((size_t)(bidx * H + h0) * N + ii) * DH + dbase) = o;
        else if (which == 1)
            *(float4*)(kb + ((size_t)(bidx * H + h0) * J + MEM + ii) * DH + dbase) = o;
        else
            *(float4*)(vb + ((size_t)(bidx * H + h0) * J + MEM + ii) * DH + dbase) = o;
    }
}

// ---------------- K1b: broadcast mem_k/mem_v into k/v rows 0..MEM-1 -------
__global__ void memkv_copy(const float* __restrict__ mem_k, const float* __restrict__ mem_v,
                           float* __restrict__ kb, float* __restrict__ vb)
{
    const int idx = blockIdx.x * 256 + threadIdx.x;  // over H*MEM*DH = 8192
    if (idx >= H * MEM * DH) return;
    const int h0 = idx / (MEM * DH);
    const int rd = idx % (MEM * DH);
    const float kvk = mem_k[idx], kvv = mem_v[idx];
#pragma unroll
    for (int bb = 0; bb < B; ++bb) {
        kb[(size_t)(bb * H + h0) * J * DH + rd] = kvk;
        vb[(size_t)(bb * H + h0) * J * DH + rd] = kvv;
    }
}

// ---------------- K2: fused talking-heads attention -----------------------
// grid (B, N/16), 256 threads. Two passes over j-tiles:
//  A: exact row stats (m,l) per mixed head h1 (online max/sum, width-16 shuffles)
//  B: recompute scores, exact p=exp(d-m)/l, post-mix to h2, PV accumulate.
__global__ __launch_bounds__(256)
void attn_fused(const float* __restrict__ qb, const float* __restrict__ kb,
                const float* __restrict__ vb, const float* __restrict__ prep,
                const float* __restrict__ postp, const float* __restrict__ hsp,
                float* __restrict__ ao)
{
    const int bidx = blockIdx.x;
    const int i0 = blockIdx.y * 16;
    const int t = threadIdx.x;

    __shared__ __align__(16) float q_s[H][16][DH];   // 32 KB
    __shared__ __align__(16) float kv_s[H][16][DH];  // 32 KB (k, then v)
    __shared__ float ps[H][16][16];                  // 8 KB post-mixed probs
    __shared__ float m_s[H][16];
    __shared__ float l_s[H][16];
    __shared__ float pre_s[H * H];
    __shared__ float post_s[H * H];
    __shared__ float slope_s[H];
    __shared__ float hs_s[H];

    if (t < H * H) { pre_s[t] = prep[t]; post_s[t] = postp[t]; }
    if (t < H) { slope_s[t] = exp2f(-(float)(t + 1)); hs_s[t] = hsp[t]; }
    if (t < H * 16) { (&m_s[0][0])[t] = -3.0e38f; (&l_s[0][0])[t] = 0.f; }

    for (int u = t; u < 2048; u += 256) {  // q tile: 8192 floats as float4
        const int h0 = u >> 8, rem = u & 255, r = rem >> 4, d4 = (rem & 15) * 4;
        *(float4*)(&q_s[h0][r][d4]) =
            *(const float4*)(qb + ((size_t)(bidx * H + h0) * N + (i0 + r)) * DH + d4);
    }
    __syncthreads();

    const int jlimit = min(J, i0 + 16 + MEM);  // multiple of 16
    const int it = t >> 4, jt = t & 15;
    const int irow = i0 + it;

    // -------- pass A: stats --------
    for (int j0 = 0; j0 < jlimit; j0 += 16) {
        __syncthreads();
        for (int u = t; u < 2048; u += 256) {
            const int h0 = u >> 8, rem = u & 255, r = rem >> 4, d4 = (rem & 15) * 4;
            *(float4*)(&kv_s[h0][r][d4]) =
                *(const float4*)(kb + ((size_t)(bidx * H + h0) * J + (j0 + r)) * DH + d4);
        }
        __syncthreads();

        float s0[H];
#pragma unroll
        for (int h0 = 0; h0 < H; ++h0) {
            float acc2 = 0.f;
#pragma unroll
            for (int d4 = 0; d4 < DH / 4; ++d4) {
                const float4 a = *(const float4*)(&q_s[h0][it][d4 * 4]);
                const float4 b2 = *(const float4*)(&kv_s[h0][jt][d4 * 4]);
                acc2 = fmaf(a.x, b2.x, acc2); acc2 = fmaf(a.y, b2.y, acc2);
                acc2 = fmaf(a.z, b2.z, acc2); acc2 = fmaf(a.w, b2.w, acc2);
            }
            s0[h0] = acc2;
        }
        const int jj = j0 + jt;
        const bool vis = (jj - MEM) <= irow;
#pragma unroll
        for (int h1 = 0; h1 < H; ++h1) {
            float d1 = 0.f;
#pragma unroll
            for (int h0 = 0; h0 < H; ++h0) d1 = fmaf(s0[h0], pre_s[h0 * H + h1], d1);
            d1 = vis ? fmaf(d1, SCALE, slope_s[h1] * (float)jj) : -3.0e38f;
            float mt = d1;
#pragma unroll
            for (int off = 8; off; off >>= 1)
                mt = fmaxf(mt, __shfl_xor(mt, off, 16));
            const float e = vis ? __expf(d1 - mt) : 0.f;
            float se = e;
#pragma unroll
            for (int off = 8; off; off >>= 1)
                se += __shfl_xor(se, off, 16);
            if (jt == 0) {
                const float mo = m_s[h1][it];
                const float mn = fmaxf(mo, mt);
                l_s[h1][it] = l_s[h1][it] * __expf(mo - mn) + se * __expf(mt - mn);
                m_s[h1][it] = mn;
            }
        }
    }
    __syncthreads();
    if (t < H * 16) (&l_s[0][0])[t] = 1.0f / (&l_s[0][0])[t];  // store 1/l
    __syncthreads();

    // -------- pass B: output --------
    float oacc[H][4];
#pragma unroll
    for (int h2 = 0; h2 < H; ++h2) {
        oacc[h2][0] = 0.f; oacc[h2][1] = 0.f; oacc[h2][2] = 0.f; oacc[h2][3] = 0.f;
    }
    const int dg4 = jt * 4;  // PV role of this thread: (row=it, d=dg4..dg4+3)

    for (int j0 = 0; j0 < jlimit; j0 += 16) {
        __syncthreads();
        for (int u = t; u < 2048; u += 256) {
            const int h0 = u >> 8, rem = u & 255, r = rem >> 4, d4 = (rem & 15) * 4;
            *(float4*)(&kv_s[h0][r][d4]) =
                *(const float4*)(kb + ((size_t)(bidx * H + h0) * J + (j0 + r)) * DH + d4);
        }
        __syncthreads();

        float s0[H];
#pragma unroll
        for (int h0 = 0; h0 < H; ++h0) {
            float acc2 = 0.f;
#pragma unroll
            for (int d4 = 0; d4 < DH / 4; ++d4) {
                const float4 a = *(const float4*)(&q_s[h0][it][d4 * 4]);
                const float4 b2 = *(const float4*)(&kv_s[h0][jt][d4 * 4]);
                acc2 = fmaf(a.x, b2.x, acc2); acc2 = fmaf(a.y, b2.y, acc2);
                acc2 = fmaf(a.z, b2.z, acc2); acc2 = fmaf(a.w, b2.w, acc2);
            }
            s0[h0] = acc2;
        }
        const int jj = j0 + jt;
        const bool vis = (jj - MEM) <= irow;
        float p[H];
#pragma unroll
        for (int h1 = 0; h1 < H; ++h1) {
            float d1 = 0.f;
#pragma unroll
            for (int h0 = 0; h0 < H; ++h0) d1 = fmaf(s0[h0], pre_s[h0 * H + h1], d1);
            d1 = fmaf(d1, SCALE, slope_s[h1] * (float)jj);
            p[h1] = vis ? __expf(d1 - m_s[h1][it]) * l_s[h1][it] : 0.f;
        }
#pragma unroll
        for (int h2 = 0; h2 < H; ++h2) {
            float pm = 0.f;
#pragma unroll
            for (int h1 = 0; h1 < H; ++h1) pm = fmaf(p[h1], post_s[h1 * H + h2], pm);
            ps[h2][it][jt] = pm;
        }
        __syncthreads();
        // overwrite kv_s with the v tile
        for (int u = t; u < 2048; u += 256) {
            const int h0 = u >> 8, rem = u & 255, r = rem >> 4, d4 = (rem & 15) * 4;
            *(float4*)(&kv_s[h0][r][d4]) =
                *(const float4*)(vb + ((size_t)(bidx * H + h0) * J + (j0 + r)) * DH + d4);
        }
        __syncthreads();
        // PV: out[h2][it][dg4..+3] += ps[h2][it][:] . v[h2][:][dg4..+3]
#pragma unroll
        for (int h2 = 0; h2 < H; ++h2) {
#pragma unroll
            for (int jt2 = 0; jt2 < 16; ++jt2) {
                const float pp = ps[h2][it][jt2];
                const float4 v4 = *(const float4*)(&kv_s[h2][jt2][dg4]);
                oacc[h2][0] = fmaf(pp, v4.x, oacc[h2][0]);
                oacc[h2][1] = fmaf(pp, v4.y, oacc[h2][1]);
                oacc[h2][2] = fmaf(pp, v4.z, oacc[h2][2]);
                oacc[h2][3] = fmaf(pp, v4.w, oacc[h2][3]);
            }
        }
    }

#pragma unroll
    for (int h2 = 0; h2 < H; ++h2) {
        float4 o;
        o.x = oacc[h2][0] * hs_s[h2];
        o.y = oacc[h2][1] * hs_s[h2];
        o.z = oacc[h2][2] * hs_s[h2];
        o.w = oacc[h2][3] * hs_s[h2];
        *(float4*)(ao + (size_t)(bidx * N + irow) * DIM + h2 * DH + dg4) = o;
    }
}

// ---------------- K4: output projection GEMM + bias -----------------------
__global__ __launch_bounds__(256)
void out_gemm(const float* __restrict__ ain, const float* __restrict__ Wo,
              const float* __restrict__ bo, float* __restrict__ out)
{
    const int m0 = blockIdx.x * 64;
    const int c0 = blockIdx.y * 64;

    __shared__ __align__(16) float As[16][68];
    __shared__ __align__(16) float Bs[16][64];

    const int t = threadIdx.x;
    const int tr = t >> 4, tc = t & 15;
    float acc[4][4];
#pragma unroll
    for (int i = 0; i < 4; ++i)
#pragma unroll
        for (int j2 = 0; j2 < 4; ++j2) acc[i][j2] = 0.f;

    const int ar = t >> 2, ac4 = (t & 3) * 4;
    const int br = t >> 4, bc4 = (t & 15) * 4;

    for (int k0 = 0; k0 < DIM; k0 += 16) {
        const float4 av = *(const float4*)(ain + (size_t)(m0 + ar) * DIM + (k0 + ac4));
        const float4 bv = *(const float4*)(Wo + (size_t)(k0 + br) * DIM + (c0 + bc4));
        __syncthreads();
        As[ac4 + 0][ar] = av.x; As[ac4 + 1][ar] = av.y;
        As[ac4 + 2][ar] = av.z; As[ac4 + 3][ar] = av.w;
        *(float4*)(&Bs[br][bc4]) = bv;
        __syncthreads();
#pragma unroll
        for (int kk = 0; kk < 16; ++kk) {
            const float4 a4 = *(const float4*)(&As[kk][tr * 4]);
            const float4 b4 = *(const float4*)(&Bs[kk][tc * 4]);
            const float aarr[4] = {a4.x, a4.y, a4.z, a4.w};
            const float barr[4] = {b4.x, b4.y, b4.z, b4.w};
#pragma unroll
            for (int i = 0; i < 4; ++i)
#pragma unroll
                for (int j2 = 0; j2 < 4; ++j2)
                    acc[i][j2] = fmaf(aarr[i], barr[j2], acc[i][j2]);
        }
    }

    const float4 bias = *(const float4*)(bo + c0 + tc * 4);
#pragma unroll
    for (int i = 0; i < 4; ++i) {
        const int m = m0 + tr * 4 + i;
        float4 o;
        o.x = acc[i][0] + bias.x; o.y = acc[i][1] + bias.y;
        o.z = acc[i][2] + bias.z; o.w = acc[i][3] + bias.w;
        *(float4*)(out + (size_t)m * DIM + c0 + tc * 4) = o;
    }
}

extern "C" void kernel_launch(void* const* d_in, const int* in_sizes, int n_in,
                              void* d_out, int out_size, void* d_ws, size_t ws_size,
                              hipStream_t stream)
{
    (void)in_sizes; (void)n_in; (void)out_size; (void)ws_size;
    const float* x      = (const float*)d_in[0];
    const float* Wq     = (const float*)d_in[1];
    const float* Wk     = (const float*)d_in[2];
    const float* Wv     = (const float*)d_in[3];
    const float* mem_k  = (const float*)d_in[4];
    const float* mem_v  = (const float*)d_in[5];
    const float* pre_p  = (const float*)d_in[6];
    const float* post_p = (const float*)d_in[7];
    const float* hs     = (const float*)d_in[8];
    const float* Wo     = (const float*)d_in[9];
    const float* bo     = (const float*)d_in[10];
    float* out = (float*)d_out;

    float* ws = (float*)d_ws;
    float* qb = ws;                                  // B*H*N*DH   = 2,097,152
    float* kb = qb + (size_t)B * H * N * DH;         // B*H*J*DH   = 2,113,536
    float* vb = kb + (size_t)B * H * J * DH;         // B*H*J*DH
    float* ao = vb + (size_t)B * H * J * DH;         // B*N*DIM    = 2,097,152

    qkv_gemm<<<dim3((B * N) / 64, DIM / 64, 3), 256, 0, stream>>>(x, Wq, Wk, Wv, qb, kb, vb);
    memkv_copy<<<dim3((H * MEM * DH + 255) / 256), 256, 0, stream>>>(mem_k, mem_v, kb, vb);
    attn_fused<<<dim3(B, N / 16), 256, 0, stream>>>(qb, kb, vb, pre_p, post_p, hs, ao);
    out_gemm<<<dim3((B * N) / 64, DIM / 64), 256, 0, stream>>>(ao, Wo, bo, out);
}

// Round 2
// 1073.265 us; speedup vs baseline: 5.1597x; 5.1597x over previous
//
#include <hip/hip_runtime.h>
#include <math.h>

namespace {
constexpr int B = 2;
constexpr int N = 2048;
constexpr int DIM = 512;
constexpr int H = 8;
constexpr int DH = 64;
constexpr int MEM = 16;
constexpr int J = MEM + N;       // 2064
constexpr int CHUNK = 256;       // j columns per chunk-block
constexpr int CMAX = 9;          // ceil(2064/256)
constexpr float SCALE = 0.125f;  // 64^-0.5
}

// ---------------- K1: fused QKV projection GEMM ----------------
__global__ __launch_bounds__(256)
void qkv_gemm(const float* __restrict__ x, const float* __restrict__ Wq,
              const float* __restrict__ Wk, const float* __restrict__ Wv,
              float* __restrict__ qb, float* __restrict__ kb, float* __restrict__ vb)
{
    const int m0 = blockIdx.x * 64;
    const int c0 = blockIdx.y * 64;
    const int which = blockIdx.z;
    const float* __restrict__ W = (which == 0) ? Wq : (which == 1) ? Wk : Wv;

    __shared__ __align__(16) float As[16][68];
    __shared__ __align__(16) float Bs[16][64];

    const int t = threadIdx.x;
    const int tr = t >> 4, tc = t & 15;
    float acc[4][4];
#pragma unroll
    for (int i = 0; i < 4; ++i)
#pragma unroll
        for (int j2 = 0; j2 < 4; ++j2) acc[i][j2] = 0.f;

    const int ar = t >> 2, ac4 = (t & 3) * 4;
    const int br = t >> 4, bc4 = (t & 15) * 4;

    for (int k0 = 0; k0 < DIM; k0 += 16) {
        const float4 av = *(const float4*)(x + (size_t)(m0 + ar) * DIM + (k0 + ac4));
        const float4 bv = *(const float4*)(W + (size_t)(k0 + br) * DIM + (c0 + bc4));
        __syncthreads();
        As[ac4 + 0][ar] = av.x; As[ac4 + 1][ar] = av.y;
        As[ac4 + 2][ar] = av.z; As[ac4 + 3][ar] = av.w;
        *(float4*)(&Bs[br][bc4]) = bv;
        __syncthreads();
#pragma unroll
        for (int kk = 0; kk < 16; ++kk) {
            const float4 a4 = *(const float4*)(&As[kk][tr * 4]);
            const float4 b4 = *(const float4*)(&Bs[kk][tc * 4]);
            const float aarr[4] = {a4.x, a4.y, a4.z, a4.w};
            const float barr[4] = {b4.x, b4.y, b4.z, b4.w};
#pragma unroll
            for (int i = 0; i < 4; ++i)
#pragma unroll
                for (int j2 = 0; j2 < 4; ++j2)
                    acc[i][j2] = fmaf(aarr[i], barr[j2], acc[i][j2]);
        }
    }

    const int h0 = c0 >> 6;
    const int dbase = tc * 4;
#pragma unroll
    for (int i = 0; i < 4; ++i) {
        const int m = m0 + tr * 4 + i;
        const int bidx = m >> 11, ii = m & (N - 1);
        const float4 o = make_float4(acc[i][0], acc[i][1], acc[i][2], acc[i][3]);
        if (which == 0)
            *(float4*)(qb + ((size_t)(bidx * H + h0) * N + ii) * DH + dbase) = o;
        else if (which == 1)
            *(float4*)(kb + ((size_t)(bidx * H + h0) * J + MEM + ii) * DH + dbase) = o;
        else
            *(float4*)(vb + ((size_t)(bidx * H + h0) * J + MEM + ii) * DH + dbase) = o;
    }
}

// ---------------- K1b: broadcast mem_k/mem_v into k/v rows 0..MEM-1 -------
__global__ void memkv_copy(const float* __restrict__ mem_k, const float* __restrict__ mem_v,
                           float* __restrict__ kb, float* __restrict__ vb)
{
    const int idx = blockIdx.x * 256 + threadIdx.x;
    if (idx >= H * MEM * DH) return;
    const int h0 = idx / (MEM * DH);
    const int rd = idx % (MEM * DH);
    const float kvk = mem_k[idx], kvv = mem_v[idx];
#pragma unroll
    for (int bb = 0; bb < B; ++bb) {
        kb[(size_t)(bb * H + h0) * J * DH + rd] = kvk;
        vb[(size_t)(bb * H + h0) * J * DH + rd] = kvv;
    }
}

// ---------------- K2a: per-chunk softmax stats ----------------------------
// grid (CMAX, N/16, B). Chunk c covers j in [c*256, min(c*256+256, jlimit)).
// Writes m_c, l_c per (h1, row) to mlbuf[(b*128+t)*9+c][0..255].
__global__ __launch_bounds__(256)
void attn_stats(const float* __restrict__ qb, const float* __restrict__ kb,
                const float* __restrict__ prep, float* __restrict__ mlbuf)
{
    const int c = blockIdx.x, tt = blockIdx.y, bidx = blockIdx.z;
    const int i0 = tt * 16;
    const int jlimit = min(J, i0 + 16 + MEM);
    const int jstart = c * CHUNK;
    if (jstart >= jlimit) return;
    const int jend = min(jstart + CHUNK, jlimit);

    __shared__ __align__(16) float q_s[H][16][68];
    __shared__ __align__(16) float k_s[H][16][68];
    __shared__ float pre_s[H * H];
    __shared__ float slope_s[H];

    const int t = threadIdx.x;
    if (t < H * H) pre_s[t] = prep[t];
    if (t < H) slope_s[t] = exp2f(-(float)(t + 1));

    for (int u = t; u < 2048; u += 256) {
        const int h0 = u >> 8, rem = u & 255, r = rem >> 4, d4 = (rem & 15) * 4;
        *(float4*)(&q_s[h0][r][d4]) =
            *(const float4*)(qb + ((size_t)(bidx * H + h0) * N + (i0 + r)) * DH + d4);
    }
    __syncthreads();

    const int it = t >> 4, jt = t & 15;
    const int irow = i0 + it;
    float m[H], l[H];
#pragma unroll
    for (int h1 = 0; h1 < H; ++h1) { m[h1] = -3.0e38f; l[h1] = 0.f; }

    for (int j0 = jstart; j0 < jend; j0 += 16) {
        __syncthreads();
        for (int u = t; u < 2048; u += 256) {
            const int h0 = u >> 8, rem = u & 255, r = rem >> 4, d4 = (rem & 15) * 4;
            *(float4*)(&k_s[h0][r][d4]) =
                *(const float4*)(kb + ((size_t)(bidx * H + h0) * J + (j0 + r)) * DH + d4);
        }
        __syncthreads();

        float s0[H];
#pragma unroll
        for (int h0 = 0; h0 < H; ++h0) {
            float acc2 = 0.f;
#pragma unroll
            for (int d4 = 0; d4 < DH / 4; ++d4) {
                const float4 a = *(const float4*)(&q_s[h0][it][d4 * 4]);
                const float4 b2 = *(const float4*)(&k_s[h0][jt][d4 * 4]);
                acc2 = fmaf(a.x, b2.x, acc2); acc2 = fmaf(a.y, b2.y, acc2);
                acc2 = fmaf(a.z, b2.z, acc2); acc2 = fmaf(a.w, b2.w, acc2);
            }
            s0[h0] = acc2;
        }
        const int jj = j0 + jt;
        const bool vis = (jj - MEM) <= irow;
#pragma unroll
        for (int h1 = 0; h1 < H; ++h1) {
            float d1 = 0.f;
#pragma unroll
            for (int h0 = 0; h0 < H; ++h0) d1 = fmaf(s0[h0], pre_s[h0 * H + h1], d1);
            d1 = vis ? fmaf(d1, SCALE, slope_s[h1] * (float)jj) : -3.0e38f;
            float mt = d1;
#pragma unroll
            for (int off = 8; off; off >>= 1)
                mt = fmaxf(mt, __shfl_xor(mt, off, 16));
            const float mn = fmaxf(m[h1], mt);
            float e = vis ? __expf(d1 - mn) : 0.f;
#pragma unroll
            for (int off = 8; off; off >>= 1)
                e += __shfl_xor(e, off, 16);
            l[h1] = l[h1] * __expf(m[h1] - mn) + e;
            m[h1] = mn;
        }
    }

    if (jt == 0) {
        float* dst = mlbuf + (size_t)((bidx * 128 + tt) * CMAX + c) * 256;
#pragma unroll
        for (int h1 = 0; h1 < H; ++h1) {
            dst[h1 * 16 + it] = m[h1];
            dst[128 + h1 * 16 + it] = l[h1];
        }
    }
}

// ---------------- K2b: reduce chunk stats to global (m, 1/l) --------------
__global__ __launch_bounds__(256)
void stats_combine(const float* __restrict__ mlbuf, float* __restrict__ glbuf)
{
    const int idx = blockIdx.x * 256 + threadIdx.x;  // B*128*128 = 32768
    const int tt = (idx >> 7) & 127;
    const int base_bt = idx >> 7;  // b*128 + t
    const int hr = idx & 127;      // h1*16 + row
    const int nc = (16 * tt + 32 + 255) >> 8;  // chunks for this tile

    float m = -3.0e38f;
    for (int c = 0; c < nc; ++c)
        m = fmaxf(m, mlbuf[((size_t)base_bt * CMAX + c) * 256 + hr]);
    float l = 0.f;
    for (int c = 0; c < nc; ++c) {
        const float* p = mlbuf + ((size_t)base_bt * CMAX + c) * 256;
        l += p[128 + hr] * __expf(p[hr] - m);
    }
    glbuf[(size_t)base_bt * 256 + hr] = m;
    glbuf[(size_t)base_bt * 256 + 128 + hr] = 1.0f / l;
}

// ---------------- K2c: per-chunk output (exact p, postmix, PV, atomic) ----
__global__ __launch_bounds__(256)
void attn_out(const float* __restrict__ qb, const float* __restrict__ kb,
              const float* __restrict__ vb, const float* __restrict__ prep,
              const float* __restrict__ postp, const float* __restrict__ hsp,
              const float* __restrict__ glbuf, float* __restrict__ ao)
{
    const int c = blockIdx.x, tt = blockIdx.y, bidx = blockIdx.z;
    const int i0 = tt * 16;
    const int jlimit = min(J, i0 + 16 + MEM);
    const int jstart = c * CHUNK;
    if (jstart >= jlimit) return;
    const int jend = min(jstart + CHUNK, jlimit);

    __shared__ __align__(16) float q_s[H][16][68];
    __shared__ __align__(16) float kv_s[H][16][68];
    __shared__ float ps[H][16][17];
    __shared__ float pre_s[H * H];
    __shared__ float post_s[H * H];
    __shared__ float slope_s[H];
    __shared__ float hs_s[H];

    const int t = threadIdx.x;
    if (t < H * H) { pre_s[t] = prep[t]; post_s[t] = postp[t]; }
    if (t < H) { slope_s[t] = exp2f(-(float)(t + 1)); hs_s[t] = hsp[t]; }

    for (int u = t; u < 2048; u += 256) {
        const int h0 = u >> 8, rem = u & 255, r = rem >> 4, d4 = (rem & 15) * 4;
        *(float4*)(&q_s[h0][r][d4]) =
            *(const float4*)(qb + ((size_t)(bidx * H + h0) * N + (i0 + r)) * DH + d4);
    }

    const int it = t >> 4, jt = t & 15;
    const int irow = i0 + it;

    float m[H], linv[H];
    {
        const float* g = glbuf + (size_t)(bidx * 128 + tt) * 256;
#pragma unroll
        for (int h1 = 0; h1 < H; ++h1) {
            m[h1] = g[h1 * 16 + it];
            linv[h1] = g[128 + h1 * 16 + it];
        }
    }
    __syncthreads();

    float oacc[H][4];
#pragma unroll
    for (int h2 = 0; h2 < H; ++h2) {
        oacc[h2][0] = 0.f; oacc[h2][1] = 0.f; oacc[h2][2] = 0.f; oacc[h2][3] = 0.f;
    }
    const int dg4 = jt * 4;

    for (int j0 = jstart; j0 < jend; j0 += 16) {
        __syncthreads();
        for (int u = t; u < 2048; u += 256) {
            const int h0 = u >> 8, rem = u & 255, r = rem >> 4, d4 = (rem & 15) * 4;
            *(float4*)(&kv_s[h0][r][d4]) =
                *(const float4*)(kb + ((size_t)(bidx * H + h0) * J + (j0 + r)) * DH + d4);
        }
        __syncthreads();

        float s0[H];
#pragma unroll
        for (int h0 = 0; h0 < H; ++h0) {
            float acc2 = 0.f;
#pragma unroll
            for (int d4 = 0; d4 < DH / 4; ++d4) {
                const float4 a = *(const float4*)(&q_s[h0][it][d4 * 4]);
                const float4 b2 = *(const float4*)(&kv_s[h0][jt][d4 * 4]);
                acc2 = fmaf(a.x, b2.x, acc2); acc2 = fmaf(a.y, b2.y, acc2);
                acc2 = fmaf(a.z, b2.z, acc2); acc2 = fmaf(a.w, b2.w, acc2);
            }
            s0[h0] = acc2;
        }
        const int jj = j0 + jt;
        const bool vis = (jj - MEM) <= irow;
        float p[H];
#pragma unroll
        for (int h1 = 0; h1 < H; ++h1) {
            float d1 = 0.f;
#pragma unroll
            for (int h0 = 0; h0 < H; ++h0) d1 = fmaf(s0[h0], pre_s[h0 * H + h1], d1);
            d1 = fmaf(d1, SCALE, slope_s[h1] * (float)jj);
            p[h1] = vis ? __expf(d1 - m[h1]) * linv[h1] : 0.f;
        }
#pragma unroll
        for (int h2 = 0; h2 < H; ++h2) {
            float pm = 0.f;
#pragma unroll
            for (int h1 = 0; h1 < H; ++h1) pm = fmaf(p[h1], post_s[h1 * H + h2], pm);
            ps[h2][it][jt] = pm;
        }
        __syncthreads();
        for (int u = t; u < 2048; u += 256) {
            const int h0 = u >> 8, rem = u & 255, r = rem >> 4, d4 = (rem & 15) * 4;
            *(float4*)(&kv_s[h0][r][d4]) =
                *(const float4*)(vb + ((size_t)(bidx * H + h0) * J + (j0 + r)) * DH + d4);
        }
        __syncthreads();
#pragma unroll
        for (int h2 = 0; h2 < H; ++h2) {
#pragma unroll
            for (int jt2 = 0; jt2 < 16; ++jt2) {
                const float pp = ps[h2][it][jt2];
                const float4 v4 = *(const float4*)(&kv_s[h2][jt2][dg4]);
                oacc[h2][0] = fmaf(pp, v4.x, oacc[h2][0]);
                oacc[h2][1] = fmaf(pp, v4.y, oacc[h2][1]);
                oacc[h2][2] = fmaf(pp, v4.z, oacc[h2][2]);
                oacc[h2][3] = fmaf(pp, v4.w, oacc[h2][3]);
            }
        }
    }

#pragma unroll
    for (int h2 = 0; h2 < H; ++h2) {
        const float s = hs_s[h2];
        float* dst = ao + ((size_t)bidx * N + irow) * DIM + h2 * DH + dg4;
        atomicAdd(dst + 0, oacc[h2][0] * s);
        atomicAdd(dst + 1, oacc[h2][1] * s);
        atomicAdd(dst + 2, oacc[h2][2] * s);
        atomicAdd(dst + 3, oacc[h2][3] * s);
    }
}

// ---------------- K4: output projection GEMM + bias -----------------------
__global__ __launch_bounds__(256)
void out_gemm(const float* __restrict__ ain, const float* __restrict__ Wo,
              const float* __restrict__ bo, float* __restrict__ out)
{
    const int m0 = blockIdx.x * 64;
    const int c0 = blockIdx.y * 64;

    __shared__ __align__(16) float As[16][68];
    __shared__ __align__(16) float Bs[16][64];

    const int t = threadIdx.x;
    const int tr = t >> 4, tc = t & 15;
    float acc[4][4];
#pragma unroll
    for (int i = 0; i < 4; ++i)
#pragma unroll
        for (int j2 = 0; j2 < 4; ++j2) acc[i][j2] = 0.f;

    const int ar = t >> 2, ac4 = (t & 3) * 4;
    const int br = t >> 4, bc4 = (t & 15) * 4;

    for (int k0 = 0; k0 < DIM; k0 += 16) {
        const float4 av = *(const float4*)(ain + (size_t)(m0 + ar) * DIM + (k0 + ac4));
        const float4 bv = *(const float4*)(Wo + (size_t)(k0 + br) * DIM + (c0 + bc4));
        __syncthreads();
        As[ac4 + 0][ar] = av.x; As[ac4 + 1][ar] = av.y;
        As[ac4 + 2][ar] = av.z; As[ac4 + 3][ar] = av.w;
        *(float4*)(&Bs[br][bc4]) = bv;
        __syncthreads();
#pragma unroll
        for (int kk = 0; kk < 16; ++kk) {
            const float4 a4 = *(const float4*)(&As[kk][tr * 4]);
            const float4 b4 = *(const float4*)(&Bs[kk][tc * 4]);
            const float aarr[4] = {a4.x, a4.y, a4.z, a4.w};
            const float barr[4] = {b4.x, b4.y, b4.z, b4.w};
#pragma unroll
            for (int i = 0; i < 4; ++i)
#pragma unroll
                for (int j2 = 0; j2 < 4; ++j2)
                    acc[i][j2] = fmaf(aarr[i], barr[j2], acc[i][j2]);
        }
    }

    const float4 bias = *(const float4*)(bo + c0 + tc * 4);
#pragma unroll
    for (int i = 0; i < 4; ++i) {
        const int m = m0 + tr * 4 + i;
        float4 o;
        o.x = acc[i][0] + bias.x; o.y = acc[i][1] + bias.y;
        o.z = acc[i][2] + bias.z; o.w = acc[i][3] + bias.w;
        *(float4*)(out + (size_t)m * DIM + c0 + tc * 4) = o;
    }
}

extern "C" void kernel_launch(void* const* d_in, const int* in_sizes, int n_in,
                              void* d_out, int out_size, void* d_ws, size_t ws_size,
                              hipStream_t stream)
{
    (void)in_sizes; (void)n_in; (void)out_size; (void)ws_size;
    const float* x      = (const float*)d_in[0];
    const float* Wq     = (const float*)d_in[1];
    const float* Wk     = (const float*)d_in[2];
    const float* Wv     = (const float*)d_in[3];
    const float* mem_k  = (const float*)d_in[4];
    const float* mem_v  = (const float*)d_in[5];
    const float* pre_p  = (const float*)d_in[6];
    const float* post_p = (const float*)d_in[7];
    const float* hs     = (const float*)d_in[8];
    const float* Wo     = (const float*)d_in[9];
    const float* bo     = (const float*)d_in[10];
    float* out = (float*)d_out;

    float* ws = (float*)d_ws;
    float* qb    = ws;                                   // 2,097,152
    float* kb    = qb + (size_t)B * H * N * DH;          // 2,113,536
    float* vb    = kb + (size_t)B * H * J * DH;          // 2,113,536
    float* ao    = vb + (size_t)B * H * J * DH;          // 2,097,152
    float* mlbuf = ao + (size_t)B * N * DIM;             // 2*128*9*256 = 589,824
    float* glbuf = mlbuf + (size_t)B * 128 * CMAX * 256; // 2*128*256   =  65,536

    qkv_gemm<<<dim3((B * N) / 64, DIM / 64, 3), 256, 0, stream>>>(x, Wq, Wk, Wv, qb, kb, vb);
    memkv_copy<<<dim3((H * MEM * DH + 255) / 256), 256, 0, stream>>>(mem_k, mem_v, kb, vb);
    hipMemsetAsync(ao, 0, (size_t)B * N * DIM * sizeof(float), stream);
    attn_stats<<<dim3(CMAX, N / 16, B), 256, 0, stream>>>(qb, kb, pre_p, mlbuf);
    stats_combine<<<dim3((B * 128 * 128) / 256), 256, 0, stream>>>(mlbuf, glbuf);
    attn_out<<<dim3(CMAX, N / 16, B), 256, 0, stream>>>(qb, kb, vb, pre_p, post_p, hs, glbuf, ao);
    out_gemm<<<dim3((B * N) / 64, DIM / 64), 256, 0, stream>>>(ao, Wo, bo, out);
}

// Round 3
// 373.297 us; speedup vs baseline: 14.8347x; 2.8751x over previous
//
#include <hip/hip_runtime.h>
#include <math.h>

namespace {
constexpr int B = 2;
constexpr int N = 2048;
constexpr int DIM = 512;
constexpr int H = 8;
constexpr int DH = 64;
constexpr int MEM = 16;
constexpr int J = MEM + N;       // 2064
constexpr int CHUNK = 256;
constexpr int CMAX = 9;
constexpr float SCALE = 0.125f;
}

typedef __attribute__((ext_vector_type(8))) short short8;
typedef __attribute__((ext_vector_type(4))) float floatx4;
typedef __attribute__((ext_vector_type(4))) unsigned short ushortx4;

__device__ inline unsigned short f2bf(float f) {
    unsigned int u = __float_as_uint(f);
    u += 0x7fffu + ((u >> 16) & 1u);   // RNE
    return (unsigned short)(u >> 16);
}

// ---------------- K1: fused QKV projection GEMM (fp32 compute, bf16 out) --
// q16 [b,h,n,64]; k16 [b,h,J,64] (rows MEM..); vt16 [b,h,64,J] (cols MEM..)
__global__ __launch_bounds__(256)
void qkv_gemm(const float* __restrict__ x, const float* __restrict__ Wq,
              const float* __restrict__ Wk, const float* __restrict__ Wv,
              unsigned short* __restrict__ q16, unsigned short* __restrict__ k16,
              unsigned short* __restrict__ vt16)
{
    const int m0 = blockIdx.x * 64;
    const int c0 = blockIdx.y * 64;
    const int which = blockIdx.z;
    const float* __restrict__ W = (which == 0) ? Wq : (which == 1) ? Wk : Wv;

    __shared__ __align__(16) float As[16][68];
    __shared__ __align__(16) float Bs[16][64];

    const int t = threadIdx.x;
    const int tr = t >> 4, tc = t & 15;
    float acc[4][4];
#pragma unroll
    for (int i = 0; i < 4; ++i)
#pragma unroll
        for (int j2 = 0; j2 < 4; ++j2) acc[i][j2] = 0.f;

    const int ar = t >> 2, ac4 = (t & 3) * 4;
    const int br = t >> 4, bc4 = (t & 15) * 4;

    for (int k0 = 0; k0 < DIM; k0 += 16) {
        const float4 av = *(const float4*)(x + (size_t)(m0 + ar) * DIM + (k0 + ac4));
        const float4 bv = *(const float4*)(W + (size_t)(k0 + br) * DIM + (c0 + bc4));
        __syncthreads();
        As[ac4 + 0][ar] = av.x; As[ac4 + 1][ar] = av.y;
        As[ac4 + 2][ar] = av.z; As[ac4 + 3][ar] = av.w;
        *(float4*)(&Bs[br][bc4]) = bv;
        __syncthreads();
#pragma unroll
        for (int kk = 0; kk < 16; ++kk) {
            const float4 a4 = *(const float4*)(&As[kk][tr * 4]);
            const float4 b4 = *(const float4*)(&Bs[kk][tc * 4]);
            const float aarr[4] = {a4.x, a4.y, a4.z, a4.w};
            const float barr[4] = {b4.x, b4.y, b4.z, b4.w};
#pragma unroll
            for (int i = 0; i < 4; ++i)
#pragma unroll
                for (int j2 = 0; j2 < 4; ++j2)
                    acc[i][j2] = fmaf(aarr[i], barr[j2], acc[i][j2]);
        }
    }

    const int h0 = c0 >> 6;   // c0 multiple of 64 -> d-within-head = tc*4
    if (which == 0) {
#pragma unroll
        for (int i = 0; i < 4; ++i) {
            const int m = m0 + tr * 4 + i;
            const int bidx = m >> 11, ii = m & (N - 1);
            ushortx4 o = { f2bf(acc[i][0]), f2bf(acc[i][1]), f2bf(acc[i][2]), f2bf(acc[i][3]) };
            *(ushortx4*)(q16 + ((size_t)(bidx * H + h0) * N + ii) * 64 + tc * 4) = o;
        }
    } else if (which == 1) {
#pragma unroll
        for (int i = 0; i < 4; ++i) {
            const int m = m0 + tr * 4 + i;
            const int bidx = m >> 11, ii = m & (N - 1);
            ushortx4 o = { f2bf(acc[i][0]), f2bf(acc[i][1]), f2bf(acc[i][2]), f2bf(acc[i][3]) };
            *(ushortx4*)(k16 + ((size_t)(bidx * H + h0) * J + MEM + ii) * 64 + tc * 4) = o;
        }
    } else {
        const int m = m0 + tr * 4;              // 4 consecutive rows, same batch
        const int bidx = m >> 11, ii = m & (N - 1);
#pragma unroll
        for (int j2 = 0; j2 < 4; ++j2) {
            ushortx4 o = { f2bf(acc[0][j2]), f2bf(acc[1][j2]), f2bf(acc[2][j2]), f2bf(acc[3][j2]) };
            *(ushortx4*)(vt16 + ((size_t)(bidx * H + h0) * 64 + (tc * 4 + j2)) * J + (MEM + ii)) = o;
        }
    }
}

// ---------------- K1b: mem_k/mem_v into k16 rows / vt16 cols 0..15 --------
__global__ void memkv_copy(const float* __restrict__ mem_k, const float* __restrict__ mem_v,
                           unsigned short* __restrict__ k16, unsigned short* __restrict__ vt16)
{
    const int idx = blockIdx.x * 256 + threadIdx.x;  // H*MEM*DH = 8192
    if (idx >= H * MEM * DH) return;
    const int h0 = idx >> 10;
    const int rd = idx & 1023;
    const int r = rd >> 6, d = rd & 63;
    const unsigned short kk = f2bf(mem_k[idx]);
    const unsigned short vv = f2bf(mem_v[idx]);
#pragma unroll
    for (int bb = 0; bb < B; ++bb) {
        k16[((size_t)(bb * H + h0) * J + r) * 64 + d] = kk;
        vt16[((size_t)(bb * H + h0) * 64 + d) * J + r] = vv;
    }
}

// ---------------- K2a: softmax denominators (analytic shift, additive) ----
// l[h1][i] = sum_j exp(SCALE*premix(qk) + slope*(j - i - MEM)); atomicAdd.
__global__ __launch_bounds__(256)
void attn_lsum(const unsigned short* __restrict__ qb, const unsigned short* __restrict__ kb,
               const float* __restrict__ prep, float* __restrict__ lbuf)
{
    const int c = blockIdx.x, tt = blockIdx.y, b = blockIdx.z;
    const int i0 = tt * 16;
    const int jlimit = min(J, i0 + 32);
    const int jstart = c * CHUNK;
    if (jstart >= jlimit) return;
    const int jend = min(jstart + CHUNK, jlimit);

    __shared__ float s_s[H][16][17];
    __shared__ float pre_s[64];
    __shared__ float slope_s[8];

    const int t = threadIdx.x;
    if (t < 64) pre_s[t] = prep[t];
    if (t < 8) slope_s[t] = exp2f(-(float)(t + 1));

    const int lane = t & 63, wave = t >> 6;
    const int m16 = lane & 15, quad = lane >> 4;
    const int it = t >> 4, jt = t & 15;
    const int irow = i0 + it;

    short8 qf[2][2];
#pragma unroll
    for (int hh = 0; hh < 2; ++hh) {
        const int h = 2 * wave + hh;
        const unsigned short* qp = qb + ((size_t)(b * H + h) * N + i0 + m16) * 64 + quad * 8;
        qf[hh][0] = *(const short8*)(qp);
        qf[hh][1] = *(const short8*)(qp + 32);
    }

    float l_acc[8];
#pragma unroll
    for (int h1 = 0; h1 < 8; ++h1) l_acc[h1] = 0.f;

    for (int j0 = jstart; j0 < jend; j0 += 16) {
        const int jrow = j0 + m16;
#pragma unroll
        for (int hh = 0; hh < 2; ++hh) {
            const int h = 2 * wave + hh;
            const unsigned short* kp = kb + ((size_t)(b * H + h) * J + jrow) * 64 + quad * 8;
            floatx4 acc = {0.f, 0.f, 0.f, 0.f};
            acc = __builtin_amdgcn_mfma_f32_16x16x32_bf16(qf[hh][0], *(const short8*)kp, acc, 0, 0, 0);
            acc = __builtin_amdgcn_mfma_f32_16x16x32_bf16(qf[hh][1], *(const short8*)(kp + 32), acc, 0, 0, 0);
#pragma unroll
            for (int r = 0; r < 4; ++r) s_s[h][quad * 4 + r][m16] = acc[r];  // row=i, col=j
        }
        __syncthreads();
        const int jj = j0 + jt;
        const bool vis = (jj - MEM) <= irow;
        float s0[8];
#pragma unroll
        for (int h0 = 0; h0 < 8; ++h0) s0[h0] = s_s[h0][it][jt];
#pragma unroll
        for (int h1 = 0; h1 < 8; ++h1) {
            float dots = 0.f;
#pragma unroll
            for (int h0 = 0; h0 < 8; ++h0) dots = fmaf(s0[h0], pre_s[h0 * 8 + h1], dots);
            if (vis)
                l_acc[h1] += __expf(fmaf(dots, SCALE, slope_s[h1] * (float)(jj - irow - MEM)));
        }
        __syncthreads();
    }

#pragma unroll
    for (int h1 = 0; h1 < 8; ++h1) {
        float v = l_acc[h1];
        v += __shfl_xor(v, 8, 16);
        v += __shfl_xor(v, 4, 16);
        v += __shfl_xor(v, 2, 16);
        v += __shfl_xor(v, 1, 16);
        if (jt == 0)
            atomicAdd(lbuf + ((size_t)(b * 128 + tt) * 8 + h1) * 16 + it, v);
    }
}

// ---------------- K2b: normalized+postmixed PV, atomicAdd into ao ---------
__global__ __launch_bounds__(256)
void attn_pv(const unsigned short* __restrict__ qb, const unsigned short* __restrict__ kb,
             const unsigned short* __restrict__ vt, const float* __restrict__ prep,
             const float* __restrict__ postp, const float* __restrict__ hsp,
             const float* __restrict__ lbuf, float* __restrict__ ao)
{
    const int c = blockIdx.x, tt = blockIdx.y, b = blockIdx.z;
    const int i0 = tt * 16;
    const int jlimit = min(J, i0 + 32);
    const int jstart = c * CHUNK;
    if (jstart >= jlimit) return;
    const int jend = min(jstart + CHUNK, jlimit);

    __shared__ float s_s[H][16][17];
    __shared__ unsigned short p2_s[H][16][40];   // cols 0..31 = j pair, pad 8
    __shared__ float pre_s[64], post_s[64];
    __shared__ float slope_s[8];
    __shared__ float linv_s[8][16];

    const int t = threadIdx.x;
    if (t < 64) { pre_s[t] = prep[t]; post_s[t] = postp[t] * hsp[t & 7]; }
    if (t < 8) slope_s[t] = exp2f(-(float)(t + 1));
    if (t < 128)
        linv_s[t >> 4][t & 15] =
            1.0f / lbuf[((size_t)(b * 128 + tt) * 8 + (t >> 4)) * 16 + (t & 15)];

    const int lane = t & 63, wave = t >> 6;
    const int m16 = lane & 15, quad = lane >> 4;
    const int it = t >> 4, jt = t & 15;
    const int irow = i0 + it;

    short8 qf[2][2];
#pragma unroll
    for (int hh = 0; hh < 2; ++hh) {
        const int h = 2 * wave + hh;
        const unsigned short* qp = qb + ((size_t)(b * H + h) * N + i0 + m16) * 64 + quad * 8;
        qf[hh][0] = *(const short8*)(qp);
        qf[hh][1] = *(const short8*)(qp + 32);
    }

    floatx4 y[2][4];
#pragma unroll
    for (int hh = 0; hh < 2; ++hh)
#pragma unroll
        for (int dt = 0; dt < 4; ++dt) y[hh][dt] = (floatx4){0.f, 0.f, 0.f, 0.f};

    for (int j0p = jstart; j0p < jend; j0p += 32) {
#pragma unroll
        for (int half = 0; half < 2; ++half) {
            const int j0 = j0p + half * 16;
            if (j0 < jend) {
                const int jrow = j0 + m16;
#pragma unroll
                for (int hh = 0; hh < 2; ++hh) {
                    const int h = 2 * wave + hh;
                    const unsigned short* kp = kb + ((size_t)(b * H + h) * J + jrow) * 64 + quad * 8;
                    floatx4 acc = {0.f, 0.f, 0.f, 0.f};
                    acc = __builtin_amdgcn_mfma_f32_16x16x32_bf16(qf[hh][0], *(const short8*)kp, acc, 0, 0, 0);
                    acc = __builtin_amdgcn_mfma_f32_16x16x32_bf16(qf[hh][1], *(const short8*)(kp + 32), acc, 0, 0, 0);
#pragma unroll
                    for (int r = 0; r < 4; ++r) s_s[h][quad * 4 + r][m16] = acc[r];
                }
            }
            __syncthreads();
            const int jj = j0 + jt;
            const bool vis = (j0 < jend) && ((jj - MEM) <= irow);
            float s0[8];
#pragma unroll
            for (int h0 = 0; h0 < 8; ++h0) s0[h0] = s_s[h0][it][jt];
            float p[8];
#pragma unroll
            for (int h1 = 0; h1 < 8; ++h1) {
                float dots = 0.f;
#pragma unroll
                for (int h0 = 0; h0 < 8; ++h0) dots = fmaf(s0[h0], pre_s[h0 * 8 + h1], dots);
                p[h1] = vis ? __expf(fmaf(dots, SCALE, slope_s[h1] * (float)(jj - irow - MEM)))
                                  * linv_s[h1][it]
                            : 0.f;
            }
#pragma unroll
            for (int h2 = 0; h2 < 8; ++h2) {
                float pm = 0.f;
#pragma unroll
                for (int h1 = 0; h1 < 8; ++h1) pm = fmaf(p[h1], post_s[h1 * 8 + h2], pm);
                p2_s[h2][it][half * 16 + jt] = f2bf(pm);
            }
            __syncthreads();
        }
        // PV over the 32-j pair: A = p2_s[h2] (K=32), B = vt (k-major)
#pragma unroll
        for (int hh = 0; hh < 2; ++hh) {
            const int h2 = 2 * wave + hh;
            const short8 pf = *(const short8*)(&p2_s[h2][m16][quad * 8]);
            const unsigned short* vbase = vt + (size_t)(b * H + h2) * 64 * J;
            int jb = j0p + quad * 8;
            if (jb > J - 8) jb = J - 8;   // masked region only; p2=0 there
#pragma unroll
            for (int dt = 0; dt < 4; ++dt) {
                const short8 vf = *(const short8*)(vbase + (size_t)(dt * 16 + m16) * J + jb);
                y[hh][dt] = __builtin_amdgcn_mfma_f32_16x16x32_bf16(pf, vf, y[hh][dt], 0, 0, 0);
            }
        }
    }

#pragma unroll
    for (int hh = 0; hh < 2; ++hh) {
        const int h2 = 2 * wave + hh;
#pragma unroll
        for (int dt = 0; dt < 4; ++dt) {
#pragma unroll
            for (int r = 0; r < 4; ++r) {
                const int i = i0 + quad * 4 + r;
                const int d = dt * 16 + m16;
                atomicAdd(ao + ((size_t)b * N + i) * DIM + h2 * 64 + d, y[hh][dt][r]);
            }
        }
    }
}

// ---------------- K4: output projection GEMM + bias (fp32) ----------------
__global__ __launch_bounds__(256)
void out_gemm(const float* __restrict__ ain, const float* __restrict__ Wo,
              const float* __restrict__ bo, float* __restrict__ out)
{
    const int m0 = blockIdx.x * 64;
    const int c0 = blockIdx.y * 64;

    __shared__ __align__(16) float As[16][68];
    __shared__ __align__(16) float Bs[16][64];

    const int t = threadIdx.x;
    const int tr = t >> 4, tc = t & 15;
    float acc[4][4];
#pragma unroll
    for (int i = 0; i < 4; ++i)
#pragma unroll
        for (int j2 = 0; j2 < 4; ++j2) acc[i][j2] = 0.f;

    const int ar = t >> 2, ac4 = (t & 3) * 4;
    const int br = t >> 4, bc4 = (t & 15) * 4;

    for (int k0 = 0; k0 < DIM; k0 += 16) {
        const float4 av = *(const float4*)(ain + (size_t)(m0 + ar) * DIM + (k0 + ac4));
        const float4 bv = *(const float4*)(Wo + (size_t)(k0 + br) * DIM + (c0 + bc4));
        __syncthreads();
        As[ac4 + 0][ar] = av.x; As[ac4 + 1][ar] = av.y;
        As[ac4 + 2][ar] = av.z; As[ac4 + 3][ar] = av.w;
        *(float4*)(&Bs[br][bc4]) = bv;
        __syncthreads();
#pragma unroll
        for (int kk = 0; kk < 16; ++kk) {
            const float4 a4 = *(const float4*)(&As[kk][tr * 4]);
            const float4 b4 = *(const float4*)(&Bs[kk][tc * 4]);
            const float aarr[4] = {a4.x, a4.y, a4.z, a4.w};
            const float barr[4] = {b4.x, b4.y, b4.z, b4.w};
#pragma unroll
            for (int i = 0; i < 4; ++i)
#pragma unroll
                for (int j2 = 0; j2 < 4; ++j2)
                    acc[i][j2] = fmaf(aarr[i], barr[j2], acc[i][j2]);
        }
    }

    const float4 bias = *(const float4*)(bo + c0 + tc * 4);
#pragma unroll
    for (int i = 0; i < 4; ++i) {
        const int m = m0 + tr * 4 + i;
        float4 o;
        o.x = acc[i][0] + bias.x; o.y = acc[i][1] + bias.y;
        o.z = acc[i][2] + bias.z; o.w = acc[i][3] + bias.w;
        *(float4*)(out + (size_t)m * DIM + c0 + tc * 4) = o;
    }
}

extern "C" void kernel_launch(void* const* d_in, const int* in_sizes, int n_in,
                              void* d_out, int out_size, void* d_ws, size_t ws_size,
                              hipStream_t stream)
{
    (void)in_sizes; (void)n_in; (void)out_size; (void)ws_size;
    const float* x      = (const float*)d_in[0];
    const float* Wq     = (const float*)d_in[1];
    const float* Wk     = (const float*)d_in[2];
    const float* Wv     = (const float*)d_in[3];
    const float* mem_k  = (const float*)d_in[4];
    const float* mem_v  = (const float*)d_in[5];
    const float* pre_p  = (const float*)d_in[6];
    const float* post_p = (const float*)d_in[7];
    const float* hs     = (const float*)d_in[8];
    const float* Wo     = (const float*)d_in[9];
    const float* bo     = (const float*)d_in[10];
    float* out = (float*)d_out;

    float* ws = (float*)d_ws;
    float* ao   = ws;                                    // B*N*DIM = 2,097,152 f
    float* lbuf = ao + (size_t)B * N * DIM;              // B*128*8*16 = 32,768 f
    unsigned short* q16 = (unsigned short*)(lbuf + (size_t)B * 128 * H * 16);
    unsigned short* k16 = q16 + (size_t)B * H * N * 64;  // q16: 2,097,152 u16
    unsigned short* v16 = k16 + (size_t)B * H * J * 64;  // k16: 2,113,536 u16

    qkv_gemm<<<dim3((B * N) / 64, DIM / 64, 3), 256, 0, stream>>>(x, Wq, Wk, Wv, q16, k16, v16);
    memkv_copy<<<dim3((H * MEM * DH + 255) / 256), 256, 0, stream>>>(mem_k, mem_v, k16, v16);
    hipMemsetAsync(ws, 0, ((size_t)B * N * DIM + (size_t)B * 128 * H * 16) * sizeof(float), stream);
    attn_lsum<<<dim3(CMAX, N / 16, B), 256, 0, stream>>>(q16, k16, pre_p, lbuf);
    attn_pv<<<dim3(CMAX, N / 16, B), 256, 0, stream>>>(q16, k16, v16, pre_p, post_p, hs, lbuf, ao);
    out_gemm<<<dim3((B * N) / 64, DIM / 64), 256, 0, stream>>>(ao, Wo, bo, out);
}

// Round 5
// 365.231 us; speedup vs baseline: 15.1623x; 1.0221x over previous
//
#include <hip/hip_runtime.h>
#include <math.h>

namespace {
constexpr int B = 2;
constexpr int N = 2048;
constexpr int DIM = 512;
constexpr int H = 8;
constexpr int DH = 64;
constexpr int MEM = 16;
constexpr int J = MEM + N;       // 2064
constexpr int CHUNK = 256;
constexpr int CMAX = 9;          // ceil(2064/256)
constexpr float SCALE = 0.125f;
}

typedef __attribute__((ext_vector_type(8))) short short8;
typedef __attribute__((ext_vector_type(4))) float floatx4;
typedef __attribute__((ext_vector_type(4))) unsigned short ushortx4;
typedef __attribute__((ext_vector_type(8))) unsigned short ushortx8;

__device__ inline unsigned short f2bf(float f) {
    unsigned int u = __float_as_uint(f);
    u += 0x7fffu + ((u >> 16) & 1u);   // RNE
    return (unsigned short)(u >> 16);
}
// pack two floats to bf16 pair (round-half-up; cheap)
__device__ inline unsigned int pk2bf(float a, float b) {
    return ((__float_as_uint(a) + 0x8000u) >> 16) |
           ((__float_as_uint(b) + 0x8000u) & 0xffff0000u);
}

// ---------------- P0: x fp32 -> bf16 ----------------
__global__ __launch_bounds__(256)
void conv_bf16(const float* __restrict__ src, unsigned short* __restrict__ dst)
{
    const int i4 = blockIdx.x * 256 + threadIdx.x;   // over nelem/4
    const float4 v = *(const float4*)(src + (size_t)i4 * 4);
    ushortx4 o = { f2bf(v.x), f2bf(v.y), f2bf(v.z), f2bf(v.w) };
    *(ushortx4*)(dst + (size_t)i4 * 4) = o;
}

// ---------------- P1: W [k][n] fp32 -> WT [n][k] bf16 (4 matrices) --------
__global__ __launch_bounds__(256)
void wt_conv(const float* __restrict__ Wq, const float* __restrict__ Wk,
             const float* __restrict__ Wv, const float* __restrict__ Wo,
             unsigned short* __restrict__ tq, unsigned short* __restrict__ tk,
             unsigned short* __restrict__ tv, unsigned short* __restrict__ to_)
{
    const int z = blockIdx.z;
    const float* __restrict__ W = (z == 0) ? Wq : (z == 1) ? Wk : (z == 2) ? Wv : Wo;
    unsigned short* __restrict__ WT = (z == 0) ? tq : (z == 1) ? tk : (z == 2) ? tv : to_;
    const int k0 = blockIdx.x * 64, n0 = blockIdx.y * 64;

    __shared__ __align__(16) unsigned short tile[64][72];
    const int t = threadIdx.x;
    const int rrow = t >> 4, rcol = (t & 15) * 4;
#pragma unroll
    for (int rr = 0; rr < 4; ++rr) {
        const int row = rrow + rr * 16;
        const float4 v = *(const float4*)(W + (size_t)(k0 + row) * DIM + n0 + rcol);
        tile[rcol + 0][row] = f2bf(v.x);
        tile[rcol + 1][row] = f2bf(v.y);
        tile[rcol + 2][row] = f2bf(v.z);
        tile[rcol + 3][row] = f2bf(v.w);
    }
    __syncthreads();
    // 4 threads per output row, 16 contiguous u16 each (two x8 stores)
    const int orow = t >> 2, oseg = (t & 3) * 16;
    *(ushortx8*)(WT + (size_t)(n0 + orow) * DIM + k0 + oseg) =
        *(const ushortx8*)(&tile[orow][oseg]);
    *(ushortx8*)(WT + (size_t)(n0 + orow) * DIM + k0 + oseg + 8) =
        *(const ushortx8*)(&tile[orow][oseg + 8]);
}

// ---------------- K1: QKV projection GEMM (bf16 MFMA, direct-global) ------
// q16 [b,h,n,64]; k16 [b,h,J,64] (rows MEM..); vt16 [b,h,64,J] (cols MEM..)
__global__ __launch_bounds__(256)
void qkv_gemm(const unsigned short* __restrict__ xbf, const unsigned short* __restrict__ tq,
              const unsigned short* __restrict__ tk, const unsigned short* __restrict__ tv,
              unsigned short* __restrict__ q16, unsigned short* __restrict__ k16,
              unsigned short* __restrict__ vt16)
{
    const int which = blockIdx.z;
    const unsigned short* __restrict__ WT = (which == 0) ? tq : (which == 1) ? tk : tv;
    const int t = threadIdx.x;
    const int lane = t & 63, w = t >> 6;
    const int iL = lane & 15, quad = lane >> 4;
    const int mb = blockIdx.x * 64 + w * 16;
    const int n0 = blockIdx.y * 64;

    floatx4 acc[4];
#pragma unroll
    for (int ng = 0; ng < 4; ++ng) acc[ng] = (floatx4){0.f, 0.f, 0.f, 0.f};

    const unsigned short* arow = xbf + (size_t)(mb + iL) * DIM + quad * 8;
#pragma unroll 4
    for (int k0 = 0; k0 < DIM; k0 += 32) {
        const short8 af = *(const short8*)(arow + k0);
#pragma unroll
        for (int ng = 0; ng < 4; ++ng) {
            const short8 bf = *(const short8*)(WT + (size_t)(n0 + ng * 16 + iL) * DIM + k0 + quad * 8);
            acc[ng] = __builtin_amdgcn_mfma_f32_16x16x32_bf16(af, bf, acc[ng], 0, 0, 0);
        }
    }

    const int h0 = n0 >> 6;
    if (which == 2) {
#pragma unroll
        for (int ng = 0; ng < 4; ++ng) {
            const int d = ng * 16 + iL;
#pragma unroll
            for (int r = 0; r < 4; ++r) {
                const int m = mb + quad * 4 + r;
                const int bb = m >> 11, ii = m & (N - 1);
                vt16[((size_t)(bb * H + h0) * 64 + d) * J + MEM + ii] = f2bf(acc[ng][r]);
            }
        }
    } else {
        unsigned short* dst = (which == 0) ? q16 : k16;
        const int rowlen = 64;
#pragma unroll
        for (int ng = 0; ng < 4; ++ng) {
            const int d = ng * 16 + iL;
#pragma unroll
            for (int r = 0; r < 4; ++r) {
                const int m = mb + quad * 4 + r;
                const int bb = m >> 11, ii = m & (N - 1);
                const size_t rowbase = (which == 0)
                    ? ((size_t)(bb * H + h0) * N + ii)
                    : ((size_t)(bb * H + h0) * J + MEM + ii);
                dst[rowbase * rowlen + d] = f2bf(acc[ng][r]);
            }
        }
    }
}

// ---------------- K1b: mem_k/mem_v into k16 rows / vt16 cols 0..15 --------
__global__ void memkv_copy(const float* __restrict__ mem_k, const float* __restrict__ mem_v,
                           unsigned short* __restrict__ k16, unsigned short* __restrict__ vt16)
{
    const int idx = blockIdx.x * 256 + threadIdx.x;  // H*MEM*DH = 8192
    if (idx >= H * MEM * DH) return;
    const int h0 = idx >> 10;
    const int rd = idx & 1023;
    const int r = rd >> 6, d = rd & 63;
    const unsigned short kk = f2bf(mem_k[idx]);
    const unsigned short vv = f2bf(mem_v[idx]);
#pragma unroll
    for (int bb = 0; bb < B; ++bb) {
        k16[((size_t)(bb * H + h0) * J + r) * 64 + d] = kk;
        vt16[((size_t)(bb * H + h0) * 64 + d) * J + r] = vv;
    }
}

// ---------------- K2a: softmax denominators (sync-free waves) -------------
// S^T = K·Q per wave; premix/alibi/exp lane-local; l accumulated in regs.
__global__ __launch_bounds__(256)
void attn_lsum(const unsigned short* __restrict__ qb, const unsigned short* __restrict__ kb,
               const float* __restrict__ prep, float* __restrict__ lbuf)
{
    const int c = blockIdx.x, tt = blockIdx.y, b = blockIdx.z;
    const int i0 = tt * 16;
    const int jlim = min(J, i0 + 32);
    const int jstart = c * CHUNK;
    if (jstart >= jlim) return;
    const int jend = min(jstart + CHUNK, jlim);

    __shared__ float pre_s[64];
    const int t = threadIdx.x;
    if (t < 64) pre_s[t] = prep[t];
    __syncthreads();

    const int lane = t & 63, w = t >> 6;
    const int iL = lane & 15, quad = lane >> 4;
    const int i = i0 + iL;

    short8 qf[H][2];
#pragma unroll
    for (int h = 0; h < H; ++h) {
        const unsigned short* qp = qb + ((size_t)(b * H + h) * N + i0 + iL) * 64 + quad * 8;
        qf[h][0] = *(const short8*)(qp);
        qf[h][1] = *(const short8*)(qp + 32);
    }

    float l_acc[H];
#pragma unroll
    for (int h1 = 0; h1 < H; ++h1) l_acc[h1] = 0.f;

    const int jw0 = jstart + w * 64;
    const int jw1 = min(jw0 + 64, jend);

    for (int j0 = jw0; j0 < jw1; j0 += 16) {
        floatx4 acc[H];
#pragma unroll
        for (int h = 0; h < H; ++h) {
            const unsigned short* kp = kb + ((size_t)(b * H + h) * J + j0 + iL) * 64 + quad * 8;
            floatx4 a = {0.f, 0.f, 0.f, 0.f};
            a = __builtin_amdgcn_mfma_f32_16x16x32_bf16(*(const short8*)kp, qf[h][0], a, 0, 0, 0);
            a = __builtin_amdgcn_mfma_f32_16x16x32_bf16(*(const short8*)(kp + 32), qf[h][1], a, 0, 0, 0);
            acc[h] = a;
        }
#pragma unroll
        for (int r = 0; r < 4; ++r) {
            const int j = j0 + quad * 4 + r;
            const bool vis = (j - MEM) <= i;
            if (!vis) continue;
            const float bias = (float)(j - i - MEM);
#pragma unroll
            for (int h1 = 0; h1 < H; ++h1) {
                float dots = 0.f;
#pragma unroll
                for (int h0 = 0; h0 < H; ++h0)
                    dots = fmaf(acc[h0][r], pre_s[h0 * 8 + h1], dots);
                l_acc[h1] += __expf(fmaf(dots, SCALE, exp2f(-(float)(h1 + 1)) * bias));
            }
        }
    }

#pragma unroll
    for (int h1 = 0; h1 < H; ++h1) {
        float v = l_acc[h1];
        v += __shfl_xor(v, 16);
        v += __shfl_xor(v, 32);
        if (quad == 0 && jw0 < jw1)
            atomicAdd(lbuf + ((size_t)(b * 128 + tt) * H + h1) * 16 + iL, v);
    }
}

// ---------------- K2b: PV with postmix (shared-LDS P2, d-split waves) -----
__global__ __launch_bounds__(256)
void attn_pv(const unsigned short* __restrict__ qb, const unsigned short* __restrict__ kb,
             const unsigned short* __restrict__ vt, const float* __restrict__ prep,
             const float* __restrict__ postp, const float* __restrict__ hsp,
             const float* __restrict__ lbuf, float* __restrict__ ao)
{
    const int c = blockIdx.x, tt = blockIdx.y, b = blockIdx.z;
    const int i0 = tt * 16;
    const int jlim = min(J, i0 + 32);
    const int jstart = c * CHUNK;
    if (jstart >= jlim) return;
    const int jend = min(jstart + CHUNK, jlim);

    __shared__ __align__(16) unsigned short p2s[H][16][136];  // [h2][i][j in window]
    __shared__ float pre_s[64], post_s[64];

    const int t = threadIdx.x;
    if (t < 64) { pre_s[t] = prep[t]; post_s[t] = postp[t] * hsp[t & 7]; }

    const int lane = t & 63, w = t >> 6;
    const int iL = lane & 15, quad = lane >> 4;
    const int i = i0 + iL;
    const int dW = w * 16 + iL;   // this wave's d for PV

    short8 qf[H][2];
#pragma unroll
    for (int h = 0; h < H; ++h) {
        const unsigned short* qp = qb + ((size_t)(b * H + h) * N + i0 + iL) * 64 + quad * 8;
        qf[h][0] = *(const short8*)(qp);
        qf[h][1] = *(const short8*)(qp + 32);
    }
    float linv[H];
#pragma unroll
    for (int h1 = 0; h1 < H; ++h1)
        linv[h1] = 1.0f / lbuf[((size_t)(b * 128 + tt) * H + h1) * 16 + iL];

    floatx4 y[H];
#pragma unroll
    for (int h2 = 0; h2 < H; ++h2) y[h2] = (floatx4){0.f, 0.f, 0.f, 0.f};
    __syncthreads();

    for (int jb0 = jstart; jb0 < jend; jb0 += 128) {
        // ---- score phase: wave w owns window cols [w*32, w*32+32) ----
#pragma unroll
        for (int sub = 0; sub < 2; ++sub) {
            const int j0 = jb0 + w * 32 + sub * 16;
            const int colb = w * 32 + sub * 16 + quad * 4;
            unsigned int pk[H][2];
#pragma unroll
            for (int h2 = 0; h2 < H; ++h2) { pk[h2][0] = 0u; pk[h2][1] = 0u; }
            if (j0 < jend) {
                floatx4 acc[H];
#pragma unroll
                for (int h = 0; h < H; ++h) {
                    const unsigned short* kp = kb + ((size_t)(b * H + h) * J + j0 + iL) * 64 + quad * 8;
                    floatx4 a = {0.f, 0.f, 0.f, 0.f};
                    a = __builtin_amdgcn_mfma_f32_16x16x32_bf16(*(const short8*)kp, qf[h][0], a, 0, 0, 0);
                    a = __builtin_amdgcn_mfma_f32_16x16x32_bf16(*(const short8*)(kp + 32), qf[h][1], a, 0, 0, 0);
                    acc[h] = a;
                }
                float p2v[H][4];
#pragma unroll
                for (int r = 0; r < 4; ++r) {
                    const int j = j0 + quad * 4 + r;
                    const bool vis = (j - MEM) <= i;
                    const float bias = (float)(j - i - MEM);
                    float p[H];
#pragma unroll
                    for (int h1 = 0; h1 < H; ++h1) {
                        float dots = 0.f;
#pragma unroll
                        for (int h0 = 0; h0 < H; ++h0)
                            dots = fmaf(acc[h0][r], pre_s[h0 * 8 + h1], dots);
                        p[h1] = vis ? __expf(fmaf(dots, SCALE, exp2f(-(float)(h1 + 1)) * bias)) * linv[h1]
                                    : 0.f;
                    }
#pragma unroll
                    for (int h2 = 0; h2 < H; ++h2) {
                        float pm = 0.f;
#pragma unroll
                        for (int h1 = 0; h1 < H; ++h1)
                            pm = fmaf(p[h1], post_s[h1 * 8 + h2], pm);
                        p2v[h2][r] = pm;
                    }
                }
#pragma unroll
                for (int h2 = 0; h2 < H; ++h2) {
                    pk[h2][0] = pk2bf(p2v[h2][0], p2v[h2][1]);
                    pk[h2][1] = pk2bf(p2v[h2][2], p2v[h2][3]);
                }
            }
#pragma unroll
            for (int h2 = 0; h2 < H; ++h2) {
                *(unsigned int*)(&p2s[h2][iL][colb]) = pk[h2][0];
                *(unsigned int*)(&p2s[h2][iL][colb + 2]) = pk[h2][1];
            }
        }
        __syncthreads();
        // ---- PV phase: wave w owns d in [w*16, w*16+16) over full window ----
        const int kcmax = (min(jend, jb0 + 128) - jb0 + 31) >> 5;
        for (int kc = 0; kc < kcmax; ++kc) {
            int jbv = jb0 + kc * 32 + quad * 8;
            if (jbv > J - 8) jbv = J - 8;   // masked region only; p2=0 there
#pragma unroll
            for (int h2 = 0; h2 < H; ++h2) {
                const short8 aF = *(const short8*)(&p2s[h2][iL][kc * 32 + quad * 8]);
                const short8 bF = *(const short8*)(vt + ((size_t)(b * H + h2) * 64 + dW) * J + jbv);
                y[h2] = __builtin_amdgcn_mfma_f32_16x16x32_bf16(aF, bF, y[h2], 0, 0, 0);
            }
        }
        __syncthreads();
    }

#pragma unroll
    for (int h2 = 0; h2 < H; ++h2) {
#pragma unroll
        for (int r = 0; r < 4; ++r) {
            const int ii = i0 + quad * 4 + r;
            atomicAdd(ao + ((size_t)b * N + ii) * DIM + h2 * 64 + dW, y[h2][r]);
        }
    }
}

// ---------------- K3: output projection GEMM + bias (bf16 MFMA) -----------
__global__ __launch_bounds__(256)
void out_gemm(const unsigned short* __restrict__ abf, const unsigned short* __restrict__ WT,
              const float* __restrict__ bo, float* __restrict__ out)
{
    const int t = threadIdx.x;
    const int lane = t & 63, w = t >> 6;
    const int iL = lane & 15, quad = lane >> 4;
    const int mb = blockIdx.x * 64 + w * 16;
    const int n0 = blockIdx.y * 64;

    floatx4 acc[4];
#pragma unroll
    for (int ng = 0; ng < 4; ++ng) acc[ng] = (floatx4){0.f, 0.f, 0.f, 0.f};

    const unsigned short* arow = abf + (size_t)(mb + iL) * DIM + quad * 8;
#pragma unroll 4
    for (int k0 = 0; k0 < DIM; k0 += 32) {
        const short8 af = *(const short8*)(arow + k0);
#pragma unroll
        for (int ng = 0; ng < 4; ++ng) {
            const short8 bf = *(const short8*)(WT + (size_t)(n0 + ng * 16 + iL) * DIM + k0 + quad * 8);
            acc[ng] = __builtin_amdgcn_mfma_f32_16x16x32_bf16(af, bf, acc[ng], 0, 0, 0);
        }
    }

#pragma unroll
    for (int ng = 0; ng < 4; ++ng) {
        const int n = n0 + ng * 16 + iL;
        const float bias = bo[n];
#pragma unroll
        for (int r = 0; r < 4; ++r) {
            const int m = mb + quad * 4 + r;
            out[(size_t)m * DIM + n] = acc[ng][r] + bias;
        }
    }
}

extern "C" void kernel_launch(void* const* d_in, const int* in_sizes, int n_in,
                              void* d_out, int out_size, void* d_ws, size_t ws_size,
                              hipStream_t stream)
{
    (void)in_sizes; (void)n_in; (void)out_size; (void)ws_size;
    const float* x      = (const float*)d_in[0];
    const float* Wq     = (const float*)d_in[1];
    const float* Wk     = (const float*)d_in[2];
    const float* Wv     = (const float*)d_in[3];
    const float* mem_k  = (const float*)d_in[4];
    const float* mem_v  = (const float*)d_in[5];
    const float* pre_p  = (const float*)d_in[6];
    const float* post_p = (const float*)d_in[7];
    const float* hs     = (const float*)d_in[8];
    const float* Wo     = (const float*)d_in[9];
    const float* bo     = (const float*)d_in[10];
    float* out = (float*)d_out;

    constexpr size_t NAO  = (size_t)B * N * DIM;        // 2,097,152
    constexpr size_t NLB  = (size_t)B * 128 * H * 16;   //    32,768
    constexpr size_t NX   = (size_t)B * N * DIM;        // 2,097,152
    constexpr size_t NW   = (size_t)DIM * DIM;          //   262,144
    constexpr size_t NQ   = (size_t)B * H * N * 64;     // 2,097,152
    constexpr size_t NK   = (size_t)B * H * J * 64;     // 2,113,536

    float* ws = (float*)d_ws;
    float* ao   = ws;
    float* lbuf = ao + NAO;
    unsigned short* xbf  = (unsigned short*)(lbuf + NLB);
    unsigned short* aobf = xbf + NX;
    unsigned short* wtq  = aobf + NX;
    unsigned short* wtk  = wtq + NW;
    unsigned short* wtv  = wtk + NW;
    unsigned short* wto  = wtv + NW;
    unsigned short* q16  = wto + NW;
    unsigned short* k16  = q16 + NQ;
    unsigned short* v16  = k16 + NK;

    conv_bf16<<<dim3(NX / 1024), 256, 0, stream>>>(x, xbf);
    wt_conv<<<dim3(8, 8, 4), 256, 0, stream>>>(Wq, Wk, Wv, Wo, wtq, wtk, wtv, wto);
    qkv_gemm<<<dim3(64, 8, 3), 256, 0, stream>>>(xbf, wtq, wtk, wtv, q16, k16, v16);
    memkv_copy<<<dim3(32), 256, 0, stream>>>(mem_k, mem_v, k16, v16);
    hipMemsetAsync(ao, 0, (NAO + NLB) * sizeof(float), stream);
    attn_lsum<<<dim3(CMAX, 128, B), 256, 0, stream>>>(q16, k16, pre_p, lbuf);
    attn_pv<<<dim3(CMAX, 128, B), 256, 0, stream>>>(q16, k16, v16, pre_p, post_p, hs, lbuf, ao);
    conv_bf16<<<dim3(NAO / 1024), 256, 0, stream>>>(ao, aobf);
    out_gemm<<<dim3(64, 8), 256, 0, stream>>>(aobf, wto, bo, out);
}